// Round 12
// baseline (295.202 us; speedup 1.0000x reference)
//
#include <hip/hip_runtime.h>
#include <hip/hip_fp16.h>
#include <math.h>

// Problem dims
#define NN   8192
#define KD   8192
#define HID  200
#define NP   224    // HID padded to 14*16
#define OUTC 5

// GEMM tiling: 1-wave blocks, 32 rows x 224 cols per wave, K-split 8
#define BM   32
#define BK   32
#define KS   8
#define KCH  (KD / KS)     // 1024
#define NT   (KCH / BK)    // 32 K-steps per block
#define TUB  896           // B tile 16B-units (224 rows x 4), PLAIN: unit = r*4 + g

typedef _Float16 f16;
typedef __attribute__((ext_vector_type(4))) _Float16 f16x4;
typedef __attribute__((ext_vector_type(8))) _Float16 f16x8;
typedef __attribute__((ext_vector_type(4))) float f32x4;

// ============ 1. W1 [8192][200] fp32 -> BW1 plain-tile fp16 ============
// tile kt (32 k) x 224 cols; unit (r=col, g=k-octet) at r*4+g.
__global__ __launch_bounds__(256) void k_prep_w1(const float* __restrict__ W1,
                                                 f16* __restrict__ Bt) {
    __shared__ float tile[64][65];
    const int bx = blockIdx.x;          // k0 = bx*64 -> tiles 2bx, 2bx+1
    const int n0 = blockIdx.y * 64;
    const int k0 = bx * 64;
    const int t = threadIdx.x;
    #pragma unroll
    for (int q = 0; q < 4; ++q) {
        int idx4 = t + q * 256;
        int kk = idx4 >> 4, nn4 = (idx4 & 15) * 4;
        int n = n0 + nn4;
        float4 v = {0.f, 0.f, 0.f, 0.f};
        if (n + 4 <= HID) v = *(const float4*)(W1 + (size_t)(k0 + kk) * HID + n);
        tile[kk][nn4 + 0] = v.x; tile[kk][nn4 + 1] = v.y;
        tile[kk][nn4 + 2] = v.z; tile[kk][nn4 + 3] = v.w;
    }
    __syncthreads();
    #pragma unroll
    for (int p2 = 0; p2 < 2; ++p2) {
        int u = t + p2 * 256;               // 0..511
        int rl = u >> 3, cc = u & 7;
        int ktl = cc >> 2, c = cc & 3;
        int r = n0 + rl;
        if (r < NP) {
            f16x8 o;
            #pragma unroll
            for (int h = 0; h < 8; ++h) o[h] = (f16)tile[ktl * 32 + c * 8 + h][rl];
            *(f16x8*)(Bt + ((size_t)(bx * 2 + ktl) * TUB + (size_t)r * 4 + c) * 8) = o;
        }
    }
}

// ============ 2. GEMM: CP[ky][row][c] (f16) = A[:, kchunk] @ B ============
// k_final-style streaming: 1 wave per block, NO LDS, NO barriers. A global->reg
// (depth-2), B frags straight from L1/L2-hot plain tiles. 2048 blocks, 8 waves/CU.
__global__ __launch_bounds__(64, 2) void k_gemm(const float* __restrict__ A,
                                                const f16* __restrict__ Bt,
                                                f16* __restrict__ CP) {
    const int lane = threadIdx.x & 63;
    const int l15 = lane & 15, g = lane >> 4;
    const int bid = blockIdx.x;
    const int ky = bid & 7;            // k-chunk; round-robin -> per-XCD B slice in L2
    const int bx = bid >> 3;
    const int m0 = bx * BM;
    const int kt0 = ky * NT;
    const size_t kc0 = (size_t)ky * KCH;

    // A rows: lane l15 covers rows m0+l15 (acc[0]) and m0+16+l15 (acc[1]); k-octet g
    const float* ap0 = A + (size_t)(m0 + l15) * KD + kc0 + (size_t)g * 8;
    const float* ap1 = ap0 + (size_t)16 * KD;
    // B frag lane element: col r = n*16 + l15, octet g -> unit r*4+g; n-stride 512 halves
    const f16* bp = Bt + ((size_t)kt0 * TUB + (size_t)(l15 * 4 + g)) * 8;

    f32x4 acc[2][14];
    #pragma unroll
    for (int m = 0; m < 2; ++m)
        #pragma unroll
        for (int n = 0; n < 14; ++n) acc[m][n] = (f32x4){0.f, 0.f, 0.f, 0.f};

    float4 va[4], vb[4];
#define LOADA(i, V) { size_t o_ = (size_t)(i) * BK;                               \
        V[0] = *(const float4*)(ap0 + o_); V[1] = *(const float4*)(ap0 + o_ + 4);  \
        V[2] = *(const float4*)(ap1 + o_); V[3] = *(const float4*)(ap1 + o_ + 4); }

    // body: B(i) loads -> cvt A(i) -> A(i+2) prefetch (newest, rides over MFMAs) -> 28 MFMA
#define BODY(i, CUR, IN) {                                                        \
        const f16* bpt_ = bp + (size_t)(i) * (TUB * 8);                           \
        f16x8 bb_[14];                                                            \
        _Pragma("unroll")                                                         \
        for (int n = 0; n < 14; ++n) bb_[n] = *(const f16x8*)(bpt_ + n * 512);    \
        f16x8 fa0_, fa1_;                                                         \
        fa0_[0]=(f16)CUR[0].x; fa0_[1]=(f16)CUR[0].y; fa0_[2]=(f16)CUR[0].z; fa0_[3]=(f16)CUR[0].w; \
        fa0_[4]=(f16)CUR[1].x; fa0_[5]=(f16)CUR[1].y; fa0_[6]=(f16)CUR[1].z; fa0_[7]=(f16)CUR[1].w; \
        fa1_[0]=(f16)CUR[2].x; fa1_[1]=(f16)CUR[2].y; fa1_[2]=(f16)CUR[2].z; fa1_[3]=(f16)CUR[2].w; \
        fa1_[4]=(f16)CUR[3].x; fa1_[5]=(f16)CUR[3].y; fa1_[6]=(f16)CUR[3].z; fa1_[7]=(f16)CUR[3].w; \
        LOADA(IN, CUR);                                                           \
        __builtin_amdgcn_sched_barrier(0);                                        \
        __builtin_amdgcn_s_setprio(1);                                            \
        _Pragma("unroll")                                                         \
        for (int n = 0; n < 14; ++n) {                                            \
            acc[0][n] = __builtin_amdgcn_mfma_f32_16x16x32_f16(fa0_, bb_[n], acc[0][n], 0, 0, 0); \
            acc[1][n] = __builtin_amdgcn_mfma_f32_16x16x32_f16(fa1_, bb_[n], acc[1][n], 0, 0, 0); } \
        __builtin_amdgcn_s_setprio(0);                                            \
        __builtin_amdgcn_sched_barrier(0); }

    LOADA(0, va);
    LOADA(1, vb);
    #pragma unroll 1
    for (int i = 0; i < NT; i += 2) {
        const int i2 = (i + 2 < NT) ? i + 2 : NT - 1;   // clamped (harmless re-load)
        const int i3 = (i + 3 < NT) ? i + 3 : NT - 1;
        BODY(i,     va, i2);
        BODY(i + 1, vb, i3);
    }
#undef LOADA
#undef BODY

    f16* o = CP + (size_t)ky * ((size_t)NN * NP);
    #pragma unroll
    for (int m = 0; m < 2; ++m) {
        #pragma unroll
        for (int n = 0; n < 14; ++n) {
            int rb = m0 + m * 16 + g * 4;
            int c = n * 16 + l15;
            #pragma unroll
            for (int r = 0; r < 4; ++r)
                o[(size_t)(rb + r) * NP + c] = (f16)acc[m][n][r];
        }
    }
}

// ============ 3. combine partials -> BS1 (plain-tile, transposed) ============
__global__ __launch_bounds__(256) void k_combine_b(const f16* __restrict__ CP,
                                                   f16* __restrict__ Bt) {
    __shared__ float tile[64][65];
    const size_t SZ = (size_t)NN * NP;
    const int bx = blockIdx.x;          // S1-row block bx*64 -> tiles 2bx, 2bx+1
    const int n0 = blockIdx.y * 64;
    const int k0 = bx * 64;
    const int t = threadIdx.x;
    #pragma unroll
    for (int q = 0; q < 4; ++q) {
        int idx4 = t + q * 256;
        int kk = idx4 >> 4, nn4 = (idx4 & 15) * 4;
        int n = n0 + nn4;
        float s0 = 0.f, s1 = 0.f, s2 = 0.f, s3 = 0.f;
        if (n < NP) {
            #pragma unroll
            for (int p = 0; p < KS; ++p) {
                f16x4 v = *(const f16x4*)(CP + (size_t)p * SZ + (size_t)(k0 + kk) * NP + n);
                s0 += (float)v[0]; s1 += (float)v[1]; s2 += (float)v[2]; s3 += (float)v[3];
            }
        }
        tile[kk][nn4 + 0] = s0; tile[kk][nn4 + 1] = s1;
        tile[kk][nn4 + 2] = s2; tile[kk][nn4 + 3] = s3;
    }
    __syncthreads();
    #pragma unroll
    for (int p2 = 0; p2 < 2; ++p2) {
        int u = t + p2 * 256;
        int rl = u >> 3, cc = u & 7;
        int ktl = cc >> 2, c = cc & 3;
        int r = n0 + rl;
        if (r < NP) {
            f16x8 o;
            #pragma unroll
            for (int h = 0; h < 8; ++h) o[h] = (f16)tile[ktl * 32 + c * 8 + h][rl];
            *(f16x8*)(Bt + ((size_t)(bx * 2 + ktl) * TUB + (size_t)r * 4 + c) * 8) = o;
        }
    }
}

// ============ 4. fused tail: H = relu(sum CP + b1); S2T = (H @ W2)^T ============
__global__ __launch_bounds__(256) void k_tail(const f16* __restrict__ CP,
                                              const float* __restrict__ b1,
                                              const float* __restrict__ W2,
                                              float* __restrict__ S2T) {
    const int tx = threadIdx.x;         // 0..31
    const int ty = threadIdx.y;         // 0..7
    const int row = blockIdx.x * 8 + ty;
    float s[OUTC] = {0.f, 0.f, 0.f, 0.f, 0.f};
    if (tx < 28) {
        const size_t SZ = (size_t)NN * NP;
        const size_t off = (size_t)row * NP + tx * 8;
        float h[8] = {0.f,0.f,0.f,0.f,0.f,0.f,0.f,0.f};
        #pragma unroll
        for (int p = 0; p < KS; ++p) {
            f16x8 v = *(const f16x8*)(CP + (size_t)p * SZ + off);
            #pragma unroll
            for (int j = 0; j < 8; ++j) h[j] += (float)v[j];
        }
        #pragma unroll
        for (int j = 0; j < 8; ++j) {
            int c = tx * 8 + j;
            if (c < HID) {
                float hv = fmaxf(h[j] + b1[c], 0.f);
                #pragma unroll
                for (int q = 0; q < OUTC; ++q) s[q] += hv * W2[c * OUTC + q];
            }
        }
    }
    #pragma unroll
    for (int q = 0; q < OUTC; ++q)
        #pragma unroll
        for (int off2 = 16; off2; off2 >>= 1) s[q] += __shfl_down(s[q], off2, 32);
    if (tx == 0) {
        #pragma unroll
        for (int q = 0; q < OUTC; ++q) S2T[(size_t)q * NN + row] = s[q];
    }
}

// ============ 5. softmax(adj @ S2 + b2) -> out (adj fp32) ============
__global__ __launch_bounds__(256) void k_final(const float* __restrict__ adj,
                                               const float* __restrict__ S2T,
                                               const float* __restrict__ b2,
                                               float* __restrict__ out) {
    __shared__ float red[4][8][OUTC];
    const int t = threadIdx.x, wave = t >> 6, lane = t & 63;
    const int row0 = blockIdx.x * 8;
    float acc[8][OUTC];
    #pragma unroll
    for (int r = 0; r < 8; ++r)
        #pragma unroll
        for (int c = 0; c < OUTC; ++c) acc[r][c] = 0.f;

    for (int jj = 0; jj < 8; ++jj) {
        int kb = (t + jj * 256) * 4;
        float4 s2[OUTC];
        #pragma unroll
        for (int c = 0; c < OUTC; ++c) s2[c] = *(const float4*)(S2T + (size_t)c * NN + kb);
        #pragma unroll
        for (int r = 0; r < 8; ++r) {
            float4 a = *(const float4*)(adj + (size_t)(row0 + r) * KD + kb);
            #pragma unroll
            for (int c = 0; c < OUTC; ++c)
                acc[r][c] += a.x * s2[c].x + a.y * s2[c].y + a.z * s2[c].z + a.w * s2[c].w;
        }
    }
    #pragma unroll
    for (int r = 0; r < 8; ++r)
        #pragma unroll
        for (int c = 0; c < OUTC; ++c) {
            float v = acc[r][c];
            #pragma unroll
            for (int off = 32; off; off >>= 1) v += __shfl_down(v, off, 64);
            if (lane == 0) red[wave][r][c] = v;
        }
    __syncthreads();
    if (t < 8) {
        int r = t;
        float lg[OUTC];
        #pragma unroll
        for (int c = 0; c < OUTC; ++c)
            lg[c] = red[0][r][c] + red[1][r][c] + red[2][r][c] + red[3][r][c] + b2[c];
        float mx = lg[0];
        #pragma unroll
        for (int c = 1; c < OUTC; ++c) mx = fmaxf(mx, lg[c]);
        float e[OUTC], ssum = 0.f;
        #pragma unroll
        for (int c = 0; c < OUTC; ++c) { e[c] = expf(lg[c] - mx); ssum += e[c]; }
        float inv = 1.0f / ssum;
        #pragma unroll
        for (int c = 0; c < OUTC; ++c) out[(size_t)(row0 + r) * OUTC + c] = e[c] * inv;
    }
}

// ===================== launcher =====================
extern "C" void kernel_launch(void* const* d_in, const int* in_sizes, int n_in,
                              void* d_out, int out_size, void* d_ws, size_t ws_size,
                              hipStream_t stream) {
    const float* x   = (const float*)d_in[0];
    const float* adj = (const float*)d_in[1];
    const float* W1  = (const float*)d_in[2];
    const float* b1  = (const float*)d_in[3];
    const float* W2  = (const float*)d_in[4];
    const float* b2  = (const float*)d_in[5];
    float* out = (float*)d_out;

    char* ws = (char*)d_ws;
    const size_t BSZ = (size_t)256 * TUB * 16;                 // 3.67 MB per B' array
    f16*   BW1 = (f16*)(ws);
    f16*   BS1 = (f16*)(ws + BSZ);
    float* S2T = (float*)(ws + 2 * BSZ);
    f16*   CP  = (f16*)(ws + 2 * BSZ + 256 * 1024);            // 8 * NN*NP f16 = 29.4 MB

    // 1. W1 -> plain-tile fp16 (B' format)
    k_prep_w1<<<dim3(128, 4), 256, 0, stream>>>(W1, BW1);
    // 2. S1 = x @ W1 (K-split fp16 partials)
    k_gemm<<<dim3(2048), 64, 0, stream>>>(x, BW1, CP);
    // 3. reduce partials -> BS1 (B' format, transposed)
    k_combine_b<<<dim3(128, 4), 256, 0, stream>>>(CP, BS1);
    // 4. adj @ S1 (K-split fp16 partials)
    k_gemm<<<dim3(2048), 64, 0, stream>>>(adj, BS1, CP);
    // 5. fused: H = relu(sum + b1); S2^T = (H @ W2)^T
    k_tail<<<dim3(NN / 8), dim3(32, 8), 0, stream>>>(CP, b1, W2, S2T);
    // 6. softmax(adj @ S2 + b2)
    k_final<<<dim3(NN / 8), 256, 0, stream>>>(adj, S2T, b2, out);
}

// Round 13
// 245.725 us; speedup vs baseline: 1.2014x; 1.2014x over previous
//
#include <hip/hip_runtime.h>
#include <hip/hip_fp16.h>
#include <math.h>

// Problem dims
#define NN   8192
#define KD   8192
#define HID  200
#define NP   224    // HID padded to 14*16
#define OUTC 5

// GEMM tiling
#define BM   128
#define BK   64
#define KS   8
#define KCH  (KD / KS)     // 1024
#define NT   (KCH / BK)    // 16 K-steps per block
#define TUB  1792          // B tile 16B-units (224 rows x 8)
#define BFSZ (NP * BK)     // halves per B LDS buffer (28 KB)
// LDS swizzle: logical unit (r, c) -> phys unit r*8 + (c ^ (r&7)); 16B units, 8 per 128B row.

typedef _Float16 f16;
typedef __attribute__((ext_vector_type(4))) _Float16 f16x4;
typedef __attribute__((ext_vector_type(8))) _Float16 f16x8;
typedef __attribute__((ext_vector_type(4))) float f32x4;

__device__ __forceinline__ void fill16(const f16* g, f16* l) {
    __builtin_amdgcn_global_load_lds(
        (const __attribute__((address_space(1))) void*)g,
        (__attribute__((address_space(3))) void*)l, 16, 0, 0);
}

// ============ 1. W1 [8192][200] fp32 -> BW1 swizzled-tile fp16 ============
__global__ __launch_bounds__(256) void k_prep_w1(const float* __restrict__ W1,
                                                 f16* __restrict__ Bsw) {
    __shared__ float tile[64][65];
    const int kt = blockIdx.x;          // 0..127
    const int n0 = blockIdx.y * 64;     // 0,64,128,192
    const int k0 = kt * 64;
    const int t = threadIdx.x;
    #pragma unroll
    for (int q = 0; q < 4; ++q) {
        int idx4 = t + q * 256;
        int kk = idx4 >> 4, nn4 = (idx4 & 15) * 4;
        int n = n0 + nn4;
        float4 v = {0.f, 0.f, 0.f, 0.f};
        if (n + 4 <= HID) v = *(const float4*)(W1 + (size_t)(k0 + kk) * HID + n);
        tile[kk][nn4 + 0] = v.x; tile[kk][nn4 + 1] = v.y;
        tile[kk][nn4 + 2] = v.z; tile[kk][nn4 + 3] = v.w;
    }
    __syncthreads();
    #pragma unroll
    for (int p2 = 0; p2 < 2; ++p2) {
        int u = t + p2 * 256;
        int rl = u >> 3, cphys = u & 7;
        int r = n0 + rl;
        if (r < NP) {
            int ck = cphys ^ (r & 7);
            f16x8 o;
            #pragma unroll
            for (int h = 0; h < 8; ++h) o[h] = (f16)tile[ck * 8 + h][rl];
            *(f16x8*)(Bsw + ((size_t)kt * TUB + r * 8 + cphys) * 8) = o;
        }
    }
}

// ============ 2. GEMM: CP[ky][row][c] (f16) = A[:, kchunk] @ B ============
// A fp32, B swizzled-tile fp16. 512 thr (8 waves 4m x 2n), 2 blocks/CU.
// Pipeline: B LDS double-buffer (fills issued 1 iter ahead), A register prefetch.
__global__ __launch_bounds__(512, 4) void k_gemm(const float* __restrict__ A,
                                                 const f16* __restrict__ Bsw,
                                                 f16* __restrict__ CP) {
    __shared__ __align__(16) f16 Ah[BM * BK];     // 16 KB
    __shared__ __align__(16) f16 Bf[2 * BFSZ];    // 2 x 28 KB

    const int t = threadIdx.x;
    const int lane = t & 63, wv = t >> 6;
    const int wm = wv >> 1, wn = wv & 1;
    const int l15 = lane & 15, g = lane >> 4;
    const int bid = blockIdx.x;
    const int ky = bid & 7;            // k-chunk; round-robin dispatch -> per-XCD B slice
    const int bx = bid >> 3;           // m-block
    const int m0 = bx * BM;
    const int kt0 = ky * NT;
    const size_t kc0 = (size_t)ky * KCH;

    // A staging: thread owns row ar, 16 halves = units ac, ac+1 (swizzled)
    const int ar = t >> 2;
    const int ac = (t & 3) * 2;
    const int swzA = ar & 7;
    f16* aw0 = &Ah[(ar * 8 + ((ac + 0) ^ swzA)) * 8];
    f16* aw1 = &Ah[(ar * 8 + ((ac + 1) ^ swzA)) * 8];
    const float* ap = A + (size_t)(m0 + ar) * KD + kc0 + (size_t)(t & 3) * 16;

    const f16* bsrc = Bsw + ((size_t)kt0 * TUB + (size_t)(wv * 64 + lane)) * 8;

    f32x4 acc[2][7];
    #pragma unroll
    for (int m = 0; m < 2; ++m)
        #pragma unroll
        for (int n = 0; n < 7; ++n) acc[m][n] = (f32x4){0.f, 0.f, 0.f, 0.f};

    float4 v0, v1, v2, v3;
#define LOADA(i) { const float* p_ = ap + (size_t)(i) * BK;            \
        v0 = *(const float4*)(p_);      v1 = *(const float4*)(p_ + 4);  \
        v2 = *(const float4*)(p_ + 8);  v3 = *(const float4*)(p_ + 12); }
#define FILLB(i, b) {                                                   \
        const f16* bs_ = bsrc + (size_t)(i) * (TUB * 8);                \
        f16* bd_ = &Bf[(size_t)(b) * BFSZ];                             \
        fill16(bs_,            bd_ + (0    + wv * 64) * 8);             \
        fill16(bs_ + 512 * 8,  bd_ + (512  + wv * 64) * 8);             \
        fill16(bs_ + 1024 * 8, bd_ + (1024 + wv * 64) * 8);             \
        if (wv < 4) fill16(bs_ + 1536 * 8, bd_ + (1536 + wv * 64) * 8); \
    }

    FILLB(0, 0);        // prologue: B tile 0 in flight
    LOADA(0);           // A tile 0 regs in flight
    for (int i = 0; i < NT; ++i) {
        // issue next B fills (other buffer; safe: trailing barrier of prev iter passed)
        if (i + 1 < NT) FILLB(i + 1, (i + 1) & 1);
        // A regs -> fp16 -> LDS; compiler's counted vmcnt wait for v0..v3 also drains FB_i
        {
            f16x8 h0, h1;
            h0[0]=(f16)v0.x; h0[1]=(f16)v0.y; h0[2]=(f16)v0.z; h0[3]=(f16)v0.w;
            h0[4]=(f16)v1.x; h0[5]=(f16)v1.y; h0[6]=(f16)v1.z; h0[7]=(f16)v1.w;
            h1[0]=(f16)v2.x; h1[1]=(f16)v2.y; h1[2]=(f16)v2.z; h1[3]=(f16)v2.w;
            h1[4]=(f16)v3.x; h1[5]=(f16)v3.y; h1[6]=(f16)v3.z; h1[7]=(f16)v3.w;
            *(f16x8*)aw0 = h0;
            *(f16x8*)aw1 = h1;
        }
        if (i + 1 < NT) LOADA(i + 1);   // next A regs in flight over MFMA
        asm volatile("s_waitcnt lgkmcnt(0)\n\ts_barrier" ::: "memory");

        const f16* bb = &Bf[(size_t)(i & 1) * BFSZ];
        __builtin_amdgcn_s_setprio(1);
        #pragma unroll
        for (int kk = 0; kk < 2; ++kk) {
            const int cu = kk * 4 + g;
            f16x8 a0, a1;
            { int r = wm * 32 + l15;      a0 = *(const f16x8*)&Ah[(r * 8 + (cu ^ (r & 7))) * 8]; }
            { int r = wm * 32 + 16 + l15; a1 = *(const f16x8*)&Ah[(r * 8 + (cu ^ (r & 7))) * 8]; }
            #pragma unroll
            for (int n = 0; n < 7; ++n) {
                int cr = wn * 112 + n * 16 + l15;
                f16x8 b = *(const f16x8*)&bb[(cr * 8 + (cu ^ (cr & 7))) * 8];
                acc[0][n] = __builtin_amdgcn_mfma_f32_16x16x32_f16(a0, b, acc[0][n], 0, 0, 0);
                acc[1][n] = __builtin_amdgcn_mfma_f32_16x16x32_f16(a1, b, acc[1][n], 0, 0, 0);
            }
        }
        __builtin_amdgcn_s_setprio(0);
        asm volatile("s_barrier" ::: "memory");   // protect Ah + B buf before next writes
    }
#undef LOADA
#undef FILLB

    f16* o = CP + (size_t)ky * ((size_t)NN * NP);
    #pragma unroll
    for (int m = 0; m < 2; ++m) {
        #pragma unroll
        for (int n = 0; n < 7; ++n) {
            int rb = m0 + wm * 32 + m * 16 + g * 4;
            int c = wn * 112 + n * 16 + l15;
            #pragma unroll
            for (int r = 0; r < 4; ++r)
                o[(size_t)(rb + r) * NP + c] = (f16)acc[m][n][r];
        }
    }
}

// ============ 3. combine partials -> BS1 (swizzled-tile, transposed) ============
__global__ __launch_bounds__(256) void k_combine_b(const f16* __restrict__ CP,
                                                   f16* __restrict__ Bsw) {
    __shared__ float tile[64][65];
    const size_t SZ = (size_t)NN * NP;
    const int kt = blockIdx.x;
    const int n0 = blockIdx.y * 64;
    const int k0 = kt * 64;
    const int t = threadIdx.x;
    #pragma unroll
    for (int q = 0; q < 4; ++q) {
        int idx4 = t + q * 256;
        int kk = idx4 >> 4, nn4 = (idx4 & 15) * 4;
        int n = n0 + nn4;
        float s0 = 0.f, s1 = 0.f, s2 = 0.f, s3 = 0.f;
        if (n < NP) {
            #pragma unroll
            for (int p = 0; p < KS; ++p) {
                f16x4 v = *(const f16x4*)(CP + (size_t)p * SZ + (size_t)(k0 + kk) * NP + n);
                s0 += (float)v[0]; s1 += (float)v[1]; s2 += (float)v[2]; s3 += (float)v[3];
            }
        }
        tile[kk][nn4 + 0] = s0; tile[kk][nn4 + 1] = s1;
        tile[kk][nn4 + 2] = s2; tile[kk][nn4 + 3] = s3;
    }
    __syncthreads();
    #pragma unroll
    for (int p2 = 0; p2 < 2; ++p2) {
        int u = t + p2 * 256;
        int rl = u >> 3, cphys = u & 7;
        int r = n0 + rl;
        if (r < NP) {
            int ck = cphys ^ (r & 7);
            f16x8 o;
            #pragma unroll
            for (int h = 0; h < 8; ++h) o[h] = (f16)tile[ck * 8 + h][rl];
            *(f16x8*)(Bsw + ((size_t)kt * TUB + r * 8 + cphys) * 8) = o;
        }
    }
}

// ============ 4. fused tail: H = relu(sum CP + b1); S2T = (H @ W2)^T ============
__global__ __launch_bounds__(256) void k_tail(const f16* __restrict__ CP,
                                              const float* __restrict__ b1,
                                              const float* __restrict__ W2,
                                              float* __restrict__ S2T) {
    const int tx = threadIdx.x;         // 0..31
    const int ty = threadIdx.y;         // 0..7
    const int row = blockIdx.x * 8 + ty;
    float s[OUTC] = {0.f, 0.f, 0.f, 0.f, 0.f};
    if (tx < 28) {
        const size_t SZ = (size_t)NN * NP;
        const size_t off = (size_t)row * NP + tx * 8;
        float h[8] = {0.f,0.f,0.f,0.f,0.f,0.f,0.f,0.f};
        #pragma unroll
        for (int p = 0; p < KS; ++p) {
            f16x8 v = *(const f16x8*)(CP + (size_t)p * SZ + off);
            #pragma unroll
            for (int j = 0; j < 8; ++j) h[j] += (float)v[j];
        }
        #pragma unroll
        for (int j = 0; j < 8; ++j) {
            int c = tx * 8 + j;
            if (c < HID) {
                float hv = fmaxf(h[j] + b1[c], 0.f);
                #pragma unroll
                for (int q = 0; q < OUTC; ++q) s[q] += hv * W2[c * OUTC + q];
            }
        }
    }
    #pragma unroll
    for (int q = 0; q < OUTC; ++q)
        #pragma unroll
        for (int off2 = 16; off2; off2 >>= 1) s[q] += __shfl_down(s[q], off2, 32);
    if (tx == 0) {
        #pragma unroll
        for (int q = 0; q < OUTC; ++q) S2T[(size_t)q * NN + row] = s[q];
    }
}

// ============ 5. softmax(adj @ S2 + b2) -> out (adj fp32) ============
__global__ __launch_bounds__(256) void k_final(const float* __restrict__ adj,
                                               const float* __restrict__ S2T,
                                               const float* __restrict__ b2,
                                               float* __restrict__ out) {
    __shared__ float red[4][8][OUTC];
    const int t = threadIdx.x, wave = t >> 6, lane = t & 63;
    const int row0 = blockIdx.x * 8;
    float acc[8][OUTC];
    #pragma unroll
    for (int r = 0; r < 8; ++r)
        #pragma unroll
        for (int c = 0; c < OUTC; ++c) acc[r][c] = 0.f;

    for (int jj = 0; jj < 8; ++jj) {
        int kb = (t + jj * 256) * 4;
        float4 s2[OUTC];
        #pragma unroll
        for (int c = 0; c < OUTC; ++c) s2[c] = *(const float4*)(S2T + (size_t)c * NN + kb);
        #pragma unroll
        for (int r = 0; r < 8; ++r) {
            float4 a = *(const float4*)(adj + (size_t)(row0 + r) * KD + kb);
            #pragma unroll
            for (int c = 0; c < OUTC; ++c)
                acc[r][c] += a.x * s2[c].x + a.y * s2[c].y + a.z * s2[c].z + a.w * s2[c].w;
        }
    }
    #pragma unroll
    for (int r = 0; r < 8; ++r)
        #pragma unroll
        for (int c = 0; c < OUTC; ++c) {
            float v = acc[r][c];
            #pragma unroll
            for (int off = 32; off; off >>= 1) v += __shfl_down(v, off, 64);
            if (lane == 0) red[wave][r][c] = v;
        }
    __syncthreads();
    if (t < 8) {
        int r = t;
        float lg[OUTC];
        #pragma unroll
        for (int c = 0; c < OUTC; ++c)
            lg[c] = red[0][r][c] + red[1][r][c] + red[2][r][c] + red[3][r][c] + b2[c];
        float mx = lg[0];
        #pragma unroll
        for (int c = 1; c < OUTC; ++c) mx = fmaxf(mx, lg[c]);
        float e[OUTC], ssum = 0.f;
        #pragma unroll
        for (int c = 0; c < OUTC; ++c) { e[c] = expf(lg[c] - mx); ssum += e[c]; }
        float inv = 1.0f / ssum;
        #pragma unroll
        for (int c = 0; c < OUTC; ++c) out[(size_t)(row0 + r) * OUTC + c] = e[c] * inv;
    }
}

// ===================== launcher =====================
extern "C" void kernel_launch(void* const* d_in, const int* in_sizes, int n_in,
                              void* d_out, int out_size, void* d_ws, size_t ws_size,
                              hipStream_t stream) {
    const float* x   = (const float*)d_in[0];
    const float* adj = (const float*)d_in[1];
    const float* W1  = (const float*)d_in[2];
    const float* b1  = (const float*)d_in[3];
    const float* W2  = (const float*)d_in[4];
    const float* b2  = (const float*)d_in[5];
    float* out = (float*)d_out;

    char* ws = (char*)d_ws;
    const size_t BSZ = (size_t)NP * KD * sizeof(f16);          // 3,670,016
    f16*   BW1 = (f16*)(ws);
    f16*   BS1 = (f16*)(ws + BSZ);
    float* S2T = (float*)(ws + 2 * BSZ);
    f16*   CP  = (f16*)(ws + 2 * BSZ + 256 * 1024);            // 8 * NN*NP f16 = 29.4 MB

    // 1. W1 -> swizzled-tile fp16 (B' format)
    k_prep_w1<<<dim3(128, 4), 256, 0, stream>>>(W1, BW1);
    // 2. S1 = x @ W1 (K-split fp16 partials)
    k_gemm<<<dim3(512), 512, 0, stream>>>(x, BW1, CP);
    // 3. reduce partials -> BS1 (B' format, transposed)
    k_combine_b<<<dim3(128, 4), 256, 0, stream>>>(CP, BS1);
    // 4. adj @ S1 (K-split fp16 partials)
    k_gemm<<<dim3(512), 512, 0, stream>>>(adj, BS1, CP);
    // 5. fused: H = relu(sum + b1); S2^T = (H @ W2)^T
    k_tail<<<dim3(NN / 8), dim3(32, 8), 0, stream>>>(CP, b1, W2, S2T);
    // 6. softmax(adj @ S2 + b2)
    k_final<<<dim3(NN / 8), 256, 0, stream>>>(adj, S2T, b2, out);
}